// Round 7
// baseline (267.737 us; speedup 1.0000x reference)
//
#include <hip/hip_runtime.h>
#include <stdint.h>

#define Bsz 16384
#define Hh  512
#define Kd  1024      // I + H
#define BM  128       // M rows per workgroup
#define BNJ 32        // j columns per workgroup (x5 gates)
#define BK  32        // K per tile
#define NT  32        // K tiles

// LDS buffer: A 8KB + B 10KB = 18KB; four buffers = 72KB -> 2 wg/CU
#define BUFB 18432

typedef __attribute__((ext_vector_type(8))) short bf16x8;
typedef __attribute__((ext_vector_type(4))) float f32x4;
typedef __attribute__((ext_vector_type(8))) unsigned short u16x8;

__device__ __forceinline__ unsigned short f2bf(float f) {
    union { float f; unsigned u; } v; v.f = f;
    unsigned u = v.u;
    return (unsigned short)((u + 0x7fffu + ((u >> 16) & 1u)) >> 16);
}
__device__ __forceinline__ float fast_tanh(float x) {
    float e = __expf(2.f * x);
    return (e - 1.f) / (e + 1.f);
}
__device__ __forceinline__ float fast_sigmoid(float x) {
    return 1.f / (1.f + __expf(-x));
}

// ---------------- pack A = [x | h_prev] -> bf16 [16384][1024] ----------------
__global__ void pack_A(const float* __restrict__ x, const float* __restrict__ h,
                       unsigned short* __restrict__ A) {
    const long total = (long)Bsz * Kd / 8;
    for (long i = (long)blockIdx.x * blockDim.x + threadIdx.x; i < total;
         i += (long)gridDim.x * blockDim.x) {
        long row = i >> 7;
        int  col = ((int)(i & 127)) << 3;
        const float* src = (col < 512) ? (x + row * 512 + col)
                                       : (h + row * 512 + (col - 512));
        float4 f0 = *(const float4*)(src);
        float4 f1 = *(const float4*)(src + 4);
        u16x8 o;
        o[0]=f2bf(f0.x); o[1]=f2bf(f0.y); o[2]=f2bf(f0.z); o[3]=f2bf(f0.w);
        o[4]=f2bf(f1.x); o[5]=f2bf(f1.y); o[6]=f2bf(f1.z); o[7]=f2bf(f1.w);
        *(u16x8*)(A + (i << 3)) = o;
    }
}

// ---- pack B into fragment-linear layout ----
// elem addr = jgrp*81920 + g*16384 + kt*1024 + kh*512 + l*8 + e
//  = W[g][ j = jgrp*16 + (l&15) ][ k = kt*64 + kh*32 + (l>>4)*8 + e ]
__global__ void pack_B(const float* __restrict__ Wxi, const float* __restrict__ Whi,
                       const float* __restrict__ Wxf, const float* __restrict__ Whf,
                       const float* __restrict__ Wxc, const float* __restrict__ Whc,
                       const float* __restrict__ Wxo, const float* __restrict__ Who,
                       const float* __restrict__ We,
                       const float* __restrict__ bxi, const float* __restrict__ bhi,
                       const float* __restrict__ bxf, const float* __restrict__ bhf,
                       const float* __restrict__ bxc, const float* __restrict__ bhc,
                       const float* __restrict__ bxo, const float* __restrict__ bho,
                       const float* __restrict__ be,
                       unsigned short* __restrict__ Bp, float* __restrict__ bias) {
    const long id = (long)blockIdx.x * blockDim.x + threadIdx.x;  // 327680 total
    if (id < 327680) {
        int blk = (int)(id >> 6);
        int l   = (int)(id & 63);
        int kh  = blk & 1;
        int kt  = (blk >> 1) & 15;
        int rest = blk >> 5;
        int g    = rest % 5;
        int jgrp = rest / 5;
        int j  = jgrp * 16 + (l & 15);
        int k0 = kt * 64 + kh * 32 + ((l >> 4) << 3);
        const float* src;
        if (g == 4) {
            src = We + (long)j * 1024 + k0;
        } else {
            const float* Wx = (g == 0) ? Wxi : (g == 1) ? Wxf : (g == 2) ? Wxc : Wxo;
            const float* Wh = (g == 0) ? Whi : (g == 1) ? Whf : (g == 2) ? Whc : Who;
            src = (k0 < 512) ? (Wx + (long)j * 512 + k0)
                             : (Wh + (long)j * 512 + (k0 - 512));
        }
        float4 f0 = *(const float4*)(src);
        float4 f1 = *(const float4*)(src + 4);
        u16x8 o;
        o[0]=f2bf(f0.x); o[1]=f2bf(f0.y); o[2]=f2bf(f0.z); o[3]=f2bf(f0.w);
        o[4]=f2bf(f1.x); o[5]=f2bf(f1.y); o[6]=f2bf(f1.z); o[7]=f2bf(f1.w);
        *(u16x8*)(Bp + (long)blk * 512 + l * 8) = o;
    }
    if (id < 2560) {
        int row = (int)id;
        int g = row >> 9, j = row & 511;
        float b;
        if (g == 4) b = be[j];
        else {
            const float* bx = (g == 0) ? bxi : (g == 1) ? bxf : (g == 2) ? bxc : bxo;
            const float* bh = (g == 0) ? bhi : (g == 1) ? bhf : (g == 2) ? bhc : bho;
            b = bx[j] + bh[j];
        }
        bias[row] = b;
    }
}

// ---------------- fused GEMM: depth-3 staging, frag-reg dbuf, 4 waves/SIMD ----------------
#define GL16(g, l) __builtin_amdgcn_global_load_lds( \
    (const __attribute__((address_space(1))) unsigned int*)(g), \
    (__attribute__((address_space(3))) unsigned int*)(l), 16, 0, 0)

#define VM_I(n)    asm volatile("s_waitcnt vmcnt(" #n ")" ::: "memory")
#define VM(n)      VM_I(n)
#define LGKM_I(n)  asm volatile("s_waitcnt lgkmcnt(" #n ")" ::: "memory")
#define LGKM(n)    LGKM_I(n)
#define BARRIER()  asm volatile("s_barrier" ::: "memory")
#define SCHED0()   __builtin_amdgcn_sched_barrier(0)

#define MF(a, b, c) __builtin_amdgcn_mfma_f32_16x16x32_bf16(a, b, c, 0, 0, 0)

// read 7 fragments of tile (for NEXT tile) into slot S from buffer at byte BO
#define RD7(S, BO) do { \
    q##S##0 = *(const bf16x8*)(bP + (BO) + 0 * 1024); \
    q##S##1 = *(const bf16x8*)(bP + (BO) + 1 * 1024); \
    q##S##2 = *(const bf16x8*)(bP + (BO) + 2 * 1024); \
    q##S##3 = *(const bf16x8*)(bP + (BO) + 3 * 1024); \
    q##S##4 = *(const bf16x8*)(bP + (BO) + 4 * 1024); \
    a##S##0 = *(const bf16x8*)(aP + (BO) + 0 * 1024); \
    a##S##1 = *(const bf16x8*)(aP + (BO) + 1 * 1024); \
} while (0)

#define MFMA10(S) do { \
    __builtin_amdgcn_s_setprio(1); \
    acc[0][0] = MF(a##S##0, q##S##0, acc[0][0]); \
    acc[0][1] = MF(a##S##1, q##S##0, acc[0][1]); \
    acc[1][0] = MF(a##S##0, q##S##1, acc[1][0]); \
    acc[1][1] = MF(a##S##1, q##S##1, acc[1][1]); \
    acc[2][0] = MF(a##S##0, q##S##2, acc[2][0]); \
    acc[2][1] = MF(a##S##1, q##S##2, acc[2][1]); \
    acc[3][0] = MF(a##S##0, q##S##3, acc[3][0]); \
    acc[3][1] = MF(a##S##1, q##S##3, acc[3][1]); \
    acc[4][0] = MF(a##S##0, q##S##4, acc[4][0]); \
    acc[4][1] = MF(a##S##1, q##S##4, acc[4][1]); \
    __builtin_amdgcn_s_setprio(0); \
} while (0)

// stage 3 units of tile T into buffer at byte offset BO (uniform per wave)
#define SG3(BO, T) do { \
    GL16(sg0 + (long)(T) * st0, lds_raw + (BO) + sd0); \
    GL16(sg1 + (long)(T) * st1, lds_raw + (BO) + sd1); \
    GL16(sg2 + (long)(T) * st2, lds_raw + (BO) + sd2); \
} while (0)

// tile T: stage T+3, read frags for T+1 into slot SN, MFMA on slot SC
#define TILE_F(T, SC, SN, RBO, SBO, STG, SYNC, WN) do { \
    if (STG) SG3(SBO, (T) + 3); \
    RD7(SN, RBO); \
    LGKM(7); SCHED0(); \
    MFMA10(SC); \
    if (SYNC) { VM(WN); BARRIER(); } \
} while (0)

// staging slot init: unit u = (wid*3+i) mod 18; u<8: A unit, else B unit
#define SLOT_INIT(i) do { \
    int u_ = wid * 3 + (i); if (u_ >= 18) u_ -= 18; \
    if (u_ < 8) { \
        int row_ = u_ * 16 + (lane >> 2); \
        sg##i = A + (brow + row_) * 1024L \
                  + (((lane & 3) ^ ((row_ >> 1) & 3)) << 3); \
        st##i = 32; \
    } else { \
        int b_ = u_ - 8; int jl_ = b_ / 5; int g_ = b_ - 5 * jl_; \
        sg##i = Bp + (long)(jblk * 2 + jl_) * 81920 + g_ * 16384 + lane * 8; \
        st##i = 512; \
    } \
    sd##i = u_ * 1024 + lane * 16; \
} while (0)

__global__ __launch_bounds__(512, 4)
void xlstm_gemm(const unsigned short* __restrict__ A,
                const unsigned short* __restrict__ Bp,
                const float* __restrict__ bias,
                const float* __restrict__ c_prev,
                float* __restrict__ out) {
    __shared__ __align__(16) unsigned char lds_raw[4 * BUFB];  // 72 KB

    const int tid  = threadIdx.x;
    const int wid  = tid >> 6;
    const int lane = tid & 63;
    const int wm   = wid >> 1;    // 0..3 : 32-row group
    const int wj   = wid & 1;     // 0..1 : 16-col group
    const int fr   = lane & 15;
    const int q    = lane >> 4;

    // T1: bijective XCD swizzle (nwg = 2048, 2048 % 8 == 0)
    const int orig = blockIdx.x;
    const int wg   = (orig & 7) * 256 + (orig >> 3);
    const int mblk = wg >> 4;     // 0..127
    const int jblk = wg & 15;     // 0..15
    const long brow = (long)mblk * BM;
    const int  bcol = jblk * BNJ;

    f32x4 acc[5][2];
#pragma unroll
    for (int g = 0; g < 5; ++g)
#pragma unroll
        for (int m = 0; m < 2; ++m)
#pragma unroll
            for (int r = 0; r < 4; ++r) acc[g][m][r] = 0.f;

    bf16x8 qA0, qA1, qA2, qA3, qA4, aA0, aA1;
    bf16x8 qB0, qB1, qB2, qB3, qB4, aB0, aB1;

    // read-side LDS base pointers (imm offsets: buf*BUFB + m/g*1024)
    const unsigned char* aP = lds_raw + wm * 2048 + fr * 64
                              + ((q ^ ((fr >> 1) & 3)) << 4);
    const unsigned char* bP = lds_raw + 8192 + wj * 5120 + lane * 16;

    // staging slots (3 per thread, 18 real units + 6 benign dups)
    const unsigned short *sg0, *sg1, *sg2;
    int st0, st1, st2, sd0, sd1, sd2;
    SLOT_INIT(0); SLOT_INIT(1); SLOT_INIT(2);

    // ---- prologue: stage tiles 0,1,2 -> bufs 0,1,2; certify 0,1; prefetch frags[0] ----
    SG3(0 * BUFB, 0);
    SG3(1 * BUFB, 1);
    SG3(2 * BUFB, 2);
    VM(3);          // tiles 0,1 certified (leaves tile 2's 3 in flight)
    BARRIER();
    RD7(A, 0 * BUFB);   // frags[0]

    // ---- main loop: tile t reads frags[t+1] from buf (t+1)%4, stages t+3 ----
    for (int t = 0; t < 28; t += 4) {
        TILE_F(t + 0, A, B, 1 * BUFB, 3 * BUFB, 1, 1, 3);
        TILE_F(t + 1, B, A, 2 * BUFB, 0 * BUFB, 1, 1, 3);
        TILE_F(t + 2, A, B, 3 * BUFB, 1 * BUFB, 1, 1, 3);
        TILE_F(t + 3, B, A, 0 * BUFB, 2 * BUFB, 1, 1, 3);
    }
    TILE_F(28, A, B, 1 * BUFB, 3 * BUFB, 1, 1, 3);  // stages tile 31
    TILE_F(29, B, A, 2 * BUFB, 0,        0, 1, 0);  // VM(0): certify staging(31)
    TILE_F(30, A, B, 3 * BUFB, 0,        0, 0, 0);  // no sync needed
    LGKM(0); SCHED0();
    MFMA10(B);                                      // tile 31

    // ---------------- epilogue (fused, in-register) ----------------
    const int j = bcol + wj * 16 + fr;
    const float bi_ = bias[j];
    const float bf_ = bias[512 + j];
    const float bc_ = bias[1024 + j];
    const float bo_ = bias[1536 + j];
    const float be_ = bias[2048 + j];
    const long mbase = brow + wm * 32 + (q << 2);
#pragma unroll
    for (int m = 0; m < 2; ++m) {
#pragma unroll
        for (int r = 0; r < 4; ++r) {
            long row = mbase + m * 16 + r;
            float gi = acc[0][m][r] + bi_;
            float gf = acc[1][m][r] + bf_;
            float gc = acc[2][m][r] + bc_;
            float go = acc[3][m][r] + bo_;
            float ge = acc[4][m][r] + be_;
            float iv = fast_sigmoid(gi);
            float fv = fast_sigmoid(gf);
            float gv = fast_tanh(gc);
            float ov = fast_sigmoid(go);
            float ef = __expf(fast_tanh(ge));
            float cp = c_prev[row * 512 + j];
            float cv = fv * cp + iv * gv;
            float hv = ov * fast_tanh(cv) * ef;
            out[row * 512 + j] = hv;
            out[(long)Bsz * 512 + row * 512 + j] = cv;
        }
    }
}

extern "C" void kernel_launch(void* const* d_in, const int* in_sizes, int n_in,
                              void* d_out, int out_size, void* d_ws, size_t ws_size,
                              hipStream_t stream) {
    const float* x      = (const float*)d_in[0];
    const float* h_prev = (const float*)d_in[1];
    const float* c_prev = (const float*)d_in[2];
    const float* Wxi = (const float*)d_in[3];
    const float* bxi = (const float*)d_in[4];
    const float* Whi = (const float*)d_in[5];
    const float* bhi = (const float*)d_in[6];
    const float* Wxf = (const float*)d_in[7];
    const float* bxf = (const float*)d_in[8];
    const float* Whf = (const float*)d_in[9];
    const float* bhf = (const float*)d_in[10];
    const float* Wxc = (const float*)d_in[11];
    const float* bxc = (const float*)d_in[12];
    const float* Whc = (const float*)d_in[13];
    const float* bhc = (const float*)d_in[14];
    const float* Wxo = (const float*)d_in[15];
    const float* bxo = (const float*)d_in[16];
    const float* Who = (const float*)d_in[17];
    const float* bho = (const float*)d_in[18];
    const float* We  = (const float*)d_in[19];
    const float* be  = (const float*)d_in[20];

    unsigned short* Abf  = (unsigned short*)d_ws;                        // 33,554,432 B
    unsigned short* Bp   = (unsigned short*)((char*)d_ws + 33554432);    //  5,242,880 B
    float*          bias = (float*)((char*)d_ws + 33554432 + 5242880);   //     10,240 B

    pack_A<<<2048, 256, 0, stream>>>(x, h_prev, Abf);
    pack_B<<<1280, 256, 0, stream>>>(Wxi, Whi, Wxf, Whf, Wxc, Whc, Wxo, Who, We,
                                     bxi, bhi, bxf, bhf, bxc, bhc, bxo, bho, be,
                                     Bp, bias);
    xlstm_gemm<<<2048, 512, 0, stream>>>(Abf, Bp, bias, c_prev, (float*)d_out);
}

// Round 8
// 121.155 us; speedup vs baseline: 2.2099x; 2.2099x over previous
//
#include <hip/hip_runtime.h>
#include <stdint.h>

#define Bsz 16384
#define Hh  512
#define Kd  1024      // I + H
#define BM  128       // M rows per workgroup
#define BNJ 32        // j columns per workgroup (x5 gates)
#define BK  32        // K per tile
#define NT  32        // K tiles

// LDS buffer: A 8KB + B 10KB = 18KB; two buffers = 36KB -> 3 wg/CU
#define BUFB 18432

typedef __attribute__((ext_vector_type(8))) short bf16x8;
typedef __attribute__((ext_vector_type(4))) float f32x4;
typedef __attribute__((ext_vector_type(8))) unsigned short u16x8;

__device__ __forceinline__ unsigned short f2bf(float f) {
    union { float f; unsigned u; } v; v.f = f;
    unsigned u = v.u;
    return (unsigned short)((u + 0x7fffu + ((u >> 16) & 1u)) >> 16);
}
__device__ __forceinline__ float fast_tanh(float x) {
    float e = __expf(2.f * x);
    return (e - 1.f) / (e + 1.f);
}
__device__ __forceinline__ float fast_sigmoid(float x) {
    return 1.f / (1.f + __expf(-x));
}

// ---------------- pack A = [x | h_prev] -> bf16 [16384][1024] ----------------
__global__ void pack_A(const float* __restrict__ x, const float* __restrict__ h,
                       unsigned short* __restrict__ A) {
    const long total = (long)Bsz * Kd / 8;
    for (long i = (long)blockIdx.x * blockDim.x + threadIdx.x; i < total;
         i += (long)gridDim.x * blockDim.x) {
        long row = i >> 7;
        int  col = ((int)(i & 127)) << 3;
        const float* src = (col < 512) ? (x + row * 512 + col)
                                       : (h + row * 512 + (col - 512));
        float4 f0 = *(const float4*)(src);
        float4 f1 = *(const float4*)(src + 4);
        u16x8 o;
        o[0]=f2bf(f0.x); o[1]=f2bf(f0.y); o[2]=f2bf(f0.z); o[3]=f2bf(f0.w);
        o[4]=f2bf(f1.x); o[5]=f2bf(f1.y); o[6]=f2bf(f1.z); o[7]=f2bf(f1.w);
        *(u16x8*)(A + (i << 3)) = o;
    }
}

// ---- pack B into fragment-linear layout ----
// elem addr = jgrp*81920 + g*16384 + kt*1024 + kh*512 + l*8 + e
//  = W[g][ j = jgrp*16 + (l&15) ][ k = kt*64 + kh*32 + (l>>4)*8 + e ]
// For BK=32 tile T: unit base = jgrp*81920 + g*16384 + T*512  (1 KB units)
__global__ void pack_B(const float* __restrict__ Wxi, const float* __restrict__ Whi,
                       const float* __restrict__ Wxf, const float* __restrict__ Whf,
                       const float* __restrict__ Wxc, const float* __restrict__ Whc,
                       const float* __restrict__ Wxo, const float* __restrict__ Who,
                       const float* __restrict__ We,
                       const float* __restrict__ bxi, const float* __restrict__ bhi,
                       const float* __restrict__ bxf, const float* __restrict__ bhf,
                       const float* __restrict__ bxc, const float* __restrict__ bhc,
                       const float* __restrict__ bxo, const float* __restrict__ bho,
                       const float* __restrict__ be,
                       unsigned short* __restrict__ Bp, float* __restrict__ bias) {
    const long id = (long)blockIdx.x * blockDim.x + threadIdx.x;  // 327680 total
    if (id < 327680) {
        int blk = (int)(id >> 6);
        int l   = (int)(id & 63);
        int kh  = blk & 1;
        int kt  = (blk >> 1) & 15;
        int rest = blk >> 5;
        int g    = rest % 5;
        int jgrp = rest / 5;
        int j  = jgrp * 16 + (l & 15);
        int k0 = kt * 64 + kh * 32 + ((l >> 4) << 3);
        const float* src;
        if (g == 4) {
            src = We + (long)j * 1024 + k0;
        } else {
            const float* Wx = (g == 0) ? Wxi : (g == 1) ? Wxf : (g == 2) ? Wxc : Wxo;
            const float* Wh = (g == 0) ? Whi : (g == 1) ? Whf : (g == 2) ? Whc : Who;
            src = (k0 < 512) ? (Wx + (long)j * 512 + k0)
                             : (Wh + (long)j * 512 + (k0 - 512));
        }
        float4 f0 = *(const float4*)(src);
        float4 f1 = *(const float4*)(src + 4);
        u16x8 o;
        o[0]=f2bf(f0.x); o[1]=f2bf(f0.y); o[2]=f2bf(f0.z); o[3]=f2bf(f0.w);
        o[4]=f2bf(f1.x); o[5]=f2bf(f1.y); o[6]=f2bf(f1.z); o[7]=f2bf(f1.w);
        *(u16x8*)(Bp + (long)blk * 512 + l * 8) = o;
    }
    if (id < 2560) {
        int row = (int)id;
        int g = row >> 9, j = row & 511;
        float b;
        if (g == 4) b = be[j];
        else {
            const float* bx = (g == 0) ? bxi : (g == 1) ? bxf : (g == 2) ? bxc : bxo;
            const float* bh = (g == 0) ? bhi : (g == 1) ? bhf : (g == 2) ? bhc : bho;
            b = bx[j] + bh[j];
        }
        bias[row] = b;
    }
}

// ---------------- fused GEMM (5-gate): BK=32, 2 bufs, 3 wg/CU ----------------
#define GL16(g, l) __builtin_amdgcn_global_load_lds( \
    (const __attribute__((address_space(1))) unsigned int*)(g), \
    (__attribute__((address_space(3))) unsigned int*)(l), 16, 0, 0)

#define VM0()      asm volatile("s_waitcnt vmcnt(0)" ::: "memory")
#define LGKM0()    asm volatile("s_waitcnt lgkmcnt(0)" ::: "memory")
#define BARRIER()  asm volatile("s_barrier" ::: "memory")
#define SCHED0()   __builtin_amdgcn_sched_barrier(0)

#define MF(a, b, c) __builtin_amdgcn_mfma_f32_16x16x32_bf16(a, b, c, 0, 0, 0)

// read all 9 fragments of the tile in buffer at byte offset RBO
#define RD9(RBO) do { \
    afA[0] = *(const bf16x8*)(aP + (RBO) + 0 * 1024); \
    afA[1] = *(const bf16x8*)(aP + (RBO) + 1 * 1024); \
    afA[2] = *(const bf16x8*)(aP + (RBO) + 2 * 1024); \
    afA[3] = *(const bf16x8*)(aP + (RBO) + 3 * 1024); \
    bq[0]  = *(const bf16x8*)(bP + (RBO) + 0 * 1024); \
    bq[1]  = *(const bf16x8*)(bP + (RBO) + 1 * 1024); \
    bq[2]  = *(const bf16x8*)(bP + (RBO) + 2 * 1024); \
    bq[3]  = *(const bf16x8*)(bP + (RBO) + 3 * 1024); \
    bq[4]  = *(const bf16x8*)(bP + (RBO) + 4 * 1024); \
} while (0)

#define MFMA20() do { \
    __builtin_amdgcn_s_setprio(1); \
    _Pragma("unroll") \
    for (int g_ = 0; g_ < 5; ++g_) { \
        acc[g_][0] = MF(afA[0], bq[g_], acc[g_][0]); \
        acc[g_][1] = MF(afA[1], bq[g_], acc[g_][1]); \
        acc[g_][2] = MF(afA[2], bq[g_], acc[g_][2]); \
        acc[g_][3] = MF(afA[3], bq[g_], acc[g_][3]); \
    } \
    __builtin_amdgcn_s_setprio(0); \
} while (0)

// stage tile T into buffer at byte offset SO: 2 A-chunks + 3 B-units per thread
#define SG5(SO, T) do { \
    GL16(asg0 + (T) * 32,  lds_raw + (SO) + adst0); \
    GL16(asg1 + (T) * 32,  lds_raw + (SO) + adst1); \
    GL16(bsg0 + (T) * 512, lds_raw + (SO) + bdo0); \
    GL16(bsg1 + (T) * 512, lds_raw + (SO) + bdo1); \
    GL16(bsg2 + (T) * 512, lds_raw + (SO) + bdo2); \
} while (0)

// one K-tile: stage T+1, read 9 frags, 20 MFMA, certify + barrier
#define TILE(RBO, SBO, T, STG, SYNC) do { \
    if (STG) SG5(SBO, (T) + 1); \
    RD9(RBO); \
    LGKM0(); SCHED0(); \
    MFMA20(); \
    if (SYNC) { VM0(); BARRIER(); } \
} while (0)

__global__ __launch_bounds__(256, 3)
void xlstm_gemm(const unsigned short* __restrict__ A,
                const unsigned short* __restrict__ Bp,
                const float* __restrict__ bias,
                const float* __restrict__ c_prev,
                float* __restrict__ out) {
    __shared__ __align__(16) unsigned char lds_raw[2 * BUFB];  // 36 KB

    const int tid  = threadIdx.x;
    const int wid  = tid >> 6;
    const int lane = tid & 63;
    const int wm   = wid >> 1;    // 0..1 : M half (64 rows)
    const int wj   = wid & 1;     // 0..1 : j half (16 cols)
    const int fr   = lane & 15;
    const int q    = lane >> 4;

    // T1: bijective XCD swizzle (nwg = 2048, 2048 % 8 == 0)
    const int orig = blockIdx.x;
    const int wg   = (orig & 7) * 256 + (orig >> 3);
    const int mblk = wg >> 4;     // 0..127
    const int jblk = wg & 15;     // 0..15
    const long brow = (long)mblk * BM;
    const int  bcol = jblk * BNJ;

    f32x4 acc[5][4];
#pragma unroll
    for (int g = 0; g < 5; ++g)
#pragma unroll
        for (int m = 0; m < 4; ++m)
#pragma unroll
            for (int r = 0; r < 4; ++r) acc[g][m][r] = 0.f;

    bf16x8 afA[4];
    bf16x8 bq[5];

    // ---- read-side LDS pointers ----
    // A row r = wm*64 + m*16 + fr at byte r*64; chunk q swizzled by (fr>>1)&3
    const unsigned char* aP = lds_raw + wm * 4096 + fr * 64
                              + ((q ^ ((fr >> 1) & 3)) << 4);
    // B unit (jl=wj, g) at 8192 + (wj*5+g)*1024; lane's frag at lane*16
    const unsigned char* bP = lds_raw + 8192 + wj * 5120 + lane * 16;

    // ---- staging pointers ----
    // A: chunk c = tid + 256*i (i<2): row = c>>2, ch = c&3, swizzled src chunk
    const int arow = tid >> 2;
    const unsigned short* asg0 = A + (brow + arow) * 1024L
                                   + (((tid & 3) ^ ((arow >> 1) & 3)) << 3);
    const unsigned short* asg1 = asg0 + 65536;   // row + 64
    const int adst0 = tid * 16;
    const int adst1 = tid * 16 + 4096;
    // B: unit u = wid + 4*i (i<3), dups u>=10 wrap to 0,1 (benign re-stage)
    const unsigned short *bsg0, *bsg1, *bsg2;
    int bdo0, bdo1, bdo2;
#define BSTG_INIT(i) do { \
    int u_ = wid + 4 * (i); if (u_ >= 10) u_ -= 10; \
    int jl_ = u_ / 5; int g_ = u_ - 5 * jl_; \
    bsg##i = Bp + (long)(jblk * 2 + jl_) * 81920 + g_ * 16384 + lane * 8; \
    bdo##i = 8192 + u_ * 1024 + lane * 16; \
} while (0)
    BSTG_INIT(0); BSTG_INIT(1); BSTG_INIT(2);
#undef BSTG_INIT

    // ---- prologue: stage tile 0 into buf0, certify ----
    SG5(0, 0);
    VM0();
    BARRIER();

    // ---- main loop: tile t reads buf t&1, stages t+1 into buf^1 ----
    for (int t = 0; t < 30; t += 2) {
        TILE(0,    BUFB, t,     1, 1);
        TILE(BUFB, 0,    t + 1, 1, 1);
    }
    TILE(0,    BUFB, 30, 1, 1);
    TILE(BUFB, 0,    31, 0, 0);

    // ---------------- epilogue (fused, in-register) ----------------
    const int j = bcol + wj * 16 + fr;
    const float bi_ = bias[j];
    const float bf_ = bias[512 + j];
    const float bc_ = bias[1024 + j];
    const float bo_ = bias[1536 + j];
    const float be_ = bias[2048 + j];
    const long mbase = brow + wm * 64 + (q << 2);
#pragma unroll
    for (int m = 0; m < 4; ++m) {
#pragma unroll
        for (int r = 0; r < 4; ++r) {
            long row = mbase + m * 16 + r;
            float gi = acc[0][m][r] + bi_;
            float gf = acc[1][m][r] + bf_;
            float gc = acc[2][m][r] + bc_;
            float go = acc[3][m][r] + bo_;
            float ge = acc[4][m][r] + be_;
            float iv = fast_sigmoid(gi);
            float fv = fast_sigmoid(gf);
            float gv = fast_tanh(gc);
            float ov = fast_sigmoid(go);
            float ef = __expf(fast_tanh(ge));
            float cp = c_prev[row * 512 + j];
            float cv = fv * cp + iv * gv;
            float hv = ov * fast_tanh(cv) * ef;
            out[row * 512 + j] = hv;
            out[(long)Bsz * 512 + row * 512 + j] = cv;
        }
    }
}

extern "C" void kernel_launch(void* const* d_in, const int* in_sizes, int n_in,
                              void* d_out, int out_size, void* d_ws, size_t ws_size,
                              hipStream_t stream) {
    const float* x      = (const float*)d_in[0];
    const float* h_prev = (const float*)d_in[1];
    const float* c_prev = (const float*)d_in[2];
    const float* Wxi = (const float*)d_in[3];
    const float* bxi = (const float*)d_in[4];
    const float* Whi = (const float*)d_in[5];
    const float* bhi = (const float*)d_in[6];
    const float* Wxf = (const float*)d_in[7];
    const float* bxf = (const float*)d_in[8];
    const float* Whf = (const float*)d_in[9];
    const float* bhf = (const float*)d_in[10];
    const float* Wxc = (const float*)d_in[11];
    const float* bxc = (const float*)d_in[12];
    const float* Whc = (const float*)d_in[13];
    const float* bhc = (const float*)d_in[14];
    const float* Wxo = (const float*)d_in[15];
    const float* bxo = (const float*)d_in[16];
    const float* Who = (const float*)d_in[17];
    const float* bho = (const float*)d_in[18];
    const float* We  = (const float*)d_in[19];
    const float* be  = (const float*)d_in[20];

    unsigned short* Abf  = (unsigned short*)d_ws;                        // 33,554,432 B
    unsigned short* Bp   = (unsigned short*)((char*)d_ws + 33554432);    //  5,242,880 B
    float*          bias = (float*)((char*)d_ws + 33554432 + 5242880);   //     10,240 B

    pack_A<<<2048, 256, 0, stream>>>(x, h_prev, Abf);
    pack_B<<<1280, 256, 0, stream>>>(Wxi, Whi, Wxf, Whf, Wxc, Whc, Wxo, Who, We,
                                     bxi, bhi, bxf, bhf, bxc, bhc, bxo, bho, be,
                                     Bp, bias);
    xlstm_gemm<<<2048, 256, 0, stream>>>(Abf, Bp, bias, c_prev, (float*)d_out);
}

// Round 9
// 119.314 us; speedup vs baseline: 2.2440x; 1.0154x over previous
//
#include <hip/hip_runtime.h>
#include <stdint.h>

#define Bsz 16384
#define Hh  512
#define Kd  1024      // I + H
#define BM  128       // M rows per workgroup
#define BNJ 32        // j columns per workgroup (x5 gates)
#define BK  32        // K per tile
#define NT  32        // K tiles

// LDS: A bufs 3 x 8KB @ {0,8192,16384}; B bufs 2 x 10KB @ 24576+{0,10240} = 44KB
#define BBASE 24576

typedef __attribute__((ext_vector_type(8))) short bf16x8;
typedef __attribute__((ext_vector_type(4))) float f32x4;
typedef __attribute__((ext_vector_type(8))) unsigned short u16x8;

__device__ __forceinline__ unsigned short f2bf(float f) {
    union { float f; unsigned u; } v; v.f = f;
    unsigned u = v.u;
    return (unsigned short)((u + 0x7fffu + ((u >> 16) & 1u)) >> 16);
}
__device__ __forceinline__ float fast_tanh(float x) {
    float e = __expf(2.f * x);
    return (e - 1.f) / (e + 1.f);
}
__device__ __forceinline__ float fast_sigmoid(float x) {
    return 1.f / (1.f + __expf(-x));
}

// ---------------- pack A = [x | h_prev] -> bf16 [16384][1024] ----------------
__global__ void pack_A(const float* __restrict__ x, const float* __restrict__ h,
                       unsigned short* __restrict__ A) {
    const long total = (long)Bsz * Kd / 8;
    for (long i = (long)blockIdx.x * blockDim.x + threadIdx.x; i < total;
         i += (long)gridDim.x * blockDim.x) {
        long row = i >> 7;
        int  col = ((int)(i & 127)) << 3;
        const float* src = (col < 512) ? (x + row * 512 + col)
                                       : (h + row * 512 + (col - 512));
        float4 f0 = *(const float4*)(src);
        float4 f1 = *(const float4*)(src + 4);
        u16x8 o;
        o[0]=f2bf(f0.x); o[1]=f2bf(f0.y); o[2]=f2bf(f0.z); o[3]=f2bf(f0.w);
        o[4]=f2bf(f1.x); o[5]=f2bf(f1.y); o[6]=f2bf(f1.z); o[7]=f2bf(f1.w);
        *(u16x8*)(A + (i << 3)) = o;
    }
}

// ---- pack B into fragment-linear layout ----
// elem addr = jgrp*81920 + g*16384 + kt*1024 + kh*512 + l*8 + e
//  = W[g][ j = jgrp*16 + (l&15) ][ k = kt*64 + kh*32 + (l>>4)*8 + e ]
__global__ void pack_B(const float* __restrict__ Wxi, const float* __restrict__ Whi,
                       const float* __restrict__ Wxf, const float* __restrict__ Whf,
                       const float* __restrict__ Wxc, const float* __restrict__ Whc,
                       const float* __restrict__ Wxo, const float* __restrict__ Who,
                       const float* __restrict__ We,
                       const float* __restrict__ bxi, const float* __restrict__ bhi,
                       const float* __restrict__ bxf, const float* __restrict__ bhf,
                       const float* __restrict__ bxc, const float* __restrict__ bhc,
                       const float* __restrict__ bxo, const float* __restrict__ bho,
                       const float* __restrict__ be,
                       unsigned short* __restrict__ Bp, float* __restrict__ bias) {
    const long id = (long)blockIdx.x * blockDim.x + threadIdx.x;  // 327680 total
    if (id < 327680) {
        int blk = (int)(id >> 6);
        int l   = (int)(id & 63);
        int kh  = blk & 1;
        int kt  = (blk >> 1) & 15;
        int rest = blk >> 5;
        int g    = rest % 5;
        int jgrp = rest / 5;
        int j  = jgrp * 16 + (l & 15);
        int k0 = kt * 64 + kh * 32 + ((l >> 4) << 3);
        const float* src;
        if (g == 4) {
            src = We + (long)j * 1024 + k0;
        } else {
            const float* Wx = (g == 0) ? Wxi : (g == 1) ? Wxf : (g == 2) ? Wxc : Wxo;
            const float* Wh = (g == 0) ? Whi : (g == 1) ? Whf : (g == 2) ? Whc : Who;
            src = (k0 < 512) ? (Wx + (long)j * 512 + k0)
                             : (Wh + (long)j * 512 + (k0 - 512));
        }
        float4 f0 = *(const float4*)(src);
        float4 f1 = *(const float4*)(src + 4);
        u16x8 o;
        o[0]=f2bf(f0.x); o[1]=f2bf(f0.y); o[2]=f2bf(f0.z); o[3]=f2bf(f0.w);
        o[4]=f2bf(f1.x); o[5]=f2bf(f1.y); o[6]=f2bf(f1.z); o[7]=f2bf(f1.w);
        *(u16x8*)(Bp + (long)blk * 512 + l * 8) = o;
    }
    if (id < 2560) {
        int row = (int)id;
        int g = row >> 9, j = row & 511;
        float b;
        if (g == 4) b = be[j];
        else {
            const float* bx = (g == 0) ? bxi : (g == 1) ? bxf : (g == 2) ? bxc : bxo;
            const float* bh = (g == 0) ? bhi : (g == 1) ? bhf : (g == 2) ? bhc : bho;
            b = bx[j] + bh[j];
        }
        bias[row] = b;
    }
}

// ------- fused GEMM: split-depth staging (A depth-2 / B depth-1), vmcnt(2), 3 wg/CU -------
#define GL16(g, l) __builtin_amdgcn_global_load_lds( \
    (const __attribute__((address_space(1))) unsigned int*)(g), \
    (__attribute__((address_space(3))) unsigned int*)(l), 16, 0, 0)

#define VM_I(n)    asm volatile("s_waitcnt vmcnt(" #n ")" ::: "memory")
#define VM(n)      VM_I(n)
#define LGKM0()    asm volatile("s_waitcnt lgkmcnt(0)" ::: "memory")
#define BARRIER()  asm volatile("s_barrier" ::: "memory")
#define SCHED0()   __builtin_amdgcn_sched_barrier(0)

#define MF(a, b, c) __builtin_amdgcn_mfma_f32_16x16x32_bf16(a, b, c, 0, 0, 0)

// read all 9 fragments: A from A-buf at ABO, B from B-buf at BBO
#define RD9(ABO, BBO) do { \
    afA[0] = *(const bf16x8*)(aP + (ABO) + 0 * 1024); \
    afA[1] = *(const bf16x8*)(aP + (ABO) + 1 * 1024); \
    afA[2] = *(const bf16x8*)(aP + (ABO) + 2 * 1024); \
    afA[3] = *(const bf16x8*)(aP + (ABO) + 3 * 1024); \
    bq[0]  = *(const bf16x8*)(bP + (BBO) + 0 * 1024); \
    bq[1]  = *(const bf16x8*)(bP + (BBO) + 1 * 1024); \
    bq[2]  = *(const bf16x8*)(bP + (BBO) + 2 * 1024); \
    bq[3]  = *(const bf16x8*)(bP + (BBO) + 3 * 1024); \
    bq[4]  = *(const bf16x8*)(bP + (BBO) + 4 * 1024); \
} while (0)

#define MFMA20() do { \
    __builtin_amdgcn_s_setprio(1); \
    _Pragma("unroll") \
    for (int g_ = 0; g_ < 5; ++g_) { \
        acc[g_][0] = MF(afA[0], bq[g_], acc[g_][0]); \
        acc[g_][1] = MF(afA[1], bq[g_], acc[g_][1]); \
        acc[g_][2] = MF(afA[2], bq[g_], acc[g_][2]); \
        acc[g_][3] = MF(afA[3], bq[g_], acc[g_][3]); \
    } \
    __builtin_amdgcn_s_setprio(0); \
} while (0)

// stage A tile T (2 GL16/thread) into A-buf at byte SAO
#define SGA2(SAO, T) do { \
    GL16(asg0 + (T) * 32, lds_raw + (SAO) + adst0); \
    GL16(asg1 + (T) * 32, lds_raw + (SAO) + adst1); \
} while (0)

// stage B tile T (3 GL16/thread) into B-buf at byte BBASE+SBO
#define SGB3(SBO, T) do { \
    GL16(bsg0 + (T) * 512, lds_raw + BBASE + (SBO) + bdo0); \
    GL16(bsg1 + (T) * 512, lds_raw + BBASE + (SBO) + bdo1); \
    GL16(bsg2 + (T) * 512, lds_raw + BBASE + (SBO) + bdo2); \
} while (0)

// one K-tile. Issue order matters: B(t+1) BEFORE A(t+2) so vmcnt(2) certifies both
// A(t+1) (leftover, oldest) and B(t+1), leaving only A(t+2) in flight.
#define TILE(ABO, BBO, SAO, SBO, T, SA, SB, WN, SYNC) do { \
    RD9(ABO, BBO); \
    if (SB) SGB3(SBO, (T) + 1); \
    if (SA) SGA2(SAO, (T) + 2); \
    LGKM0(); SCHED0(); \
    MFMA20(); \
    if (SYNC) { VM(WN); BARRIER(); } \
} while (0)

__global__ __launch_bounds__(256, 3)
void xlstm_gemm(const unsigned short* __restrict__ A,
                const unsigned short* __restrict__ Bp,
                const float* __restrict__ bias,
                const float* __restrict__ c_prev,
                float* __restrict__ out) {
    __shared__ __align__(16) unsigned char lds_raw[45056];  // 44 KB

    const int tid  = threadIdx.x;
    const int wid  = tid >> 6;
    const int lane = tid & 63;
    const int wm   = wid >> 1;    // 0..1 : M half (64 rows)
    const int wj   = wid & 1;     // 0..1 : j half (16 cols)
    const int fr   = lane & 15;
    const int q    = lane >> 4;

    // T1: bijective XCD swizzle (nwg = 2048, 2048 % 8 == 0)
    const int orig = blockIdx.x;
    const int wg   = (orig & 7) * 256 + (orig >> 3);
    const int mblk = wg >> 4;     // 0..127
    const int jblk = wg & 15;     // 0..15
    const long brow = (long)mblk * BM;
    const int  bcol = jblk * BNJ;

    f32x4 acc[5][4];
#pragma unroll
    for (int g = 0; g < 5; ++g)
#pragma unroll
        for (int m = 0; m < 4; ++m)
#pragma unroll
            for (int r = 0; r < 4; ++r) acc[g][m][r] = 0.f;

    bf16x8 afA[4];
    bf16x8 bq[5];

    // ---- read-side LDS pointers ----
    const unsigned char* aP = lds_raw + wm * 4096 + fr * 64
                              + ((q ^ ((fr >> 1) & 3)) << 4);
    const unsigned char* bP = lds_raw + BBASE + wj * 5120 + lane * 16;

    // ---- staging pointers ----
    const int arow = tid >> 2;
    const unsigned short* asg0 = A + (brow + arow) * 1024L
                                   + (((tid & 3) ^ ((arow >> 1) & 3)) << 3);
    const unsigned short* asg1 = asg0 + 65536;   // row + 64
    const int adst0 = tid * 16;
    const int adst1 = tid * 16 + 4096;
    const unsigned short *bsg0, *bsg1, *bsg2;
    int bdo0, bdo1, bdo2;
#define BSTG_INIT(i) do { \
    int u_ = wid + 4 * (i); if (u_ >= 10) u_ -= 10; \
    int jl_ = u_ / 5; int g_ = u_ - 5 * jl_; \
    bsg##i = Bp + (long)(jblk * 2 + jl_) * 81920 + g_ * 16384 + lane * 8; \
    bdo##i = u_ * 1024 + lane * 16; \
} while (0)
    BSTG_INIT(0); BSTG_INIT(1); BSTG_INIT(2);
#undef BSTG_INIT

    // ---- prologue: B(0)->Bbuf0, A(0)->Abuf0, A(1)->Abuf1; certify B0,A0 ----
    SGB3(0, 0);
    SGA2(0, 0);
    SGA2(8192, 1);
    VM(2);           // completes B0(3)+A0(2); A1's 2 stay in flight
    BARRIER();

    // ---- main loop (period 6: A bufs mod 3, B bufs mod 2) ----
    for (int t = 0; t < 30; t += 6) {
        TILE(0,     0,     16384, 10240, t + 0, 1, 1, 2, 1);
        TILE(8192,  10240, 0,     0,     t + 1, 1, 1, 2, 1);
        TILE(16384, 0,     8192,  10240, t + 2, 1, 1, 2, 1);
        TILE(0,     10240, 16384, 0,     t + 3, 1, 1, 2, 1);
        TILE(8192,  0,     0,     10240, t + 4, 1, 1, 2, 1);
        TILE(16384, 10240, 8192,  0,     t + 5, 1, 1, 2, 1);
    }
    // tile 30: stage B(31) only; drain everything (A31 + B31)
    TILE(0,    0,     0, 10240, 30, 0, 1, 0, 1);
    // tile 31: compute only
    TILE(8192, 10240, 0, 0,     31, 0, 0, 0, 0);

    // ---------------- epilogue (fused, in-register) ----------------
    const int j = bcol + wj * 16 + fr;
    const float bi_ = bias[j];
    const float bf_ = bias[512 + j];
    const float bc_ = bias[1024 + j];
    const float bo_ = bias[1536 + j];
    const float be_ = bias[2048 + j];
    const long mbase = brow + wm * 64 + (q << 2);
#pragma unroll
    for (int m = 0; m < 4; ++m) {
#pragma unroll
        for (int r = 0; r < 4; ++r) {
            long row = mbase + m * 16 + r;
            float gi = acc[0][m][r] + bi_;
            float gf = acc[1][m][r] + bf_;
            float gc = acc[2][m][r] + bc_;
            float go = acc[3][m][r] + bo_;
            float ge = acc[4][m][r] + be_;
            float iv = fast_sigmoid(gi);
            float fv = fast_sigmoid(gf);
            float gv = fast_tanh(gc);
            float ov = fast_sigmoid(go);
            float ef = __expf(fast_tanh(ge));
            float cp = c_prev[row * 512 + j];
            float cv = fv * cp + iv * gv;
            float hv = ov * fast_tanh(cv) * ef;
            out[row * 512 + j] = hv;
            out[(long)Bsz * 512 + row * 512 + j] = cv;
        }
    }
}

extern "C" void kernel_launch(void* const* d_in, const int* in_sizes, int n_in,
                              void* d_out, int out_size, void* d_ws, size_t ws_size,
                              hipStream_t stream) {
    const float* x      = (const float*)d_in[0];
    const float* h_prev = (const float*)d_in[1];
    const float* c_prev = (const float*)d_in[2];
    const float* Wxi = (const float*)d_in[3];
    const float* bxi = (const float*)d_in[4];
    const float* Whi = (const float*)d_in[5];
    const float* bhi = (const float*)d_in[6];
    const float* Wxf = (const float*)d_in[7];
    const float* bxf = (const float*)d_in[8];
    const float* Whf = (const float*)d_in[9];
    const float* bhf = (const float*)d_in[10];
    const float* Wxc = (const float*)d_in[11];
    const float* bxc = (const float*)d_in[12];
    const float* Whc = (const float*)d_in[13];
    const float* bhc = (const float*)d_in[14];
    const float* Wxo = (const float*)d_in[15];
    const float* bxo = (const float*)d_in[16];
    const float* Who = (const float*)d_in[17];
    const float* bho = (const float*)d_in[18];
    const float* We  = (const float*)d_in[19];
    const float* be  = (const float*)d_in[20];

    unsigned short* Abf  = (unsigned short*)d_ws;                        // 33,554,432 B
    unsigned short* Bp   = (unsigned short*)((char*)d_ws + 33554432);    //  5,242,880 B
    float*          bias = (float*)((char*)d_ws + 33554432 + 5242880);   //     10,240 B

    pack_A<<<2048, 256, 0, stream>>>(x, h_prev, Abf);
    pack_B<<<1280, 256, 0, stream>>>(Wxi, Whi, Wxf, Whf, Wxc, Whc, Wxo, Who, We,
                                     bxi, bhi, bxf, bhf, bxc, bhc, bxo, bho, be,
                                     Bp, bias);
    xlstm_gemm<<<2048, 256, 0, stream>>>(Abf, Bp, bias, c_prev, (float*)d_out);
}